// Round 1
// baseline (110.028 us; speedup 1.0000x reference)
//
#include <hip/hip_runtime.h>

// MultiThresholdLIFSpike: x [T=16, B=32, C=128, H=32, W=32] f32, raw thresholds [4] f32.
// Recurrence over T per spatial element:
//   u = 0.25*mem*(1-spike) + x_t
//   s = sum_k sigmoid(10*(u - thr_k)),  thr_k = sigmoid(raw_k)
//   mem = u; spike = s; out[t] = s
// Memory-bound streaming: 256MB in + 256MB out, one pass.

#define T_STEPS 16
#define NTHR 4

__device__ __forceinline__ float fast_sigmoid(float z) {
    // 1 / (1 + exp(-z)); exp->v_exp_f32, rcp->v_rcp_f32
    return __builtin_amdgcn_rcpf(1.0f + __expf(-z));
}

__global__ __launch_bounds__(256) void lif_spike_kernel(
    const float* __restrict__ x,
    const float* __restrict__ raw_thr,
    float* __restrict__ out,
    int n4 /* number of float4 groups per timestep */) {

    int i = blockIdx.x * blockDim.x + threadIdx.x;
    if (i >= n4) return;

    // thresholds (scalar-cached loads, 4 elems)
    float thr[NTHR];
#pragma unroll
    for (int k = 0; k < NTHR; ++k) {
        thr[k] = fast_sigmoid(raw_thr[k]);
    }

    const float4* __restrict__ xv = reinterpret_cast<const float4*>(x);
    float4* __restrict__ ov = reinterpret_cast<float4*>(out);

    float mem0 = 0.f, mem1 = 0.f, mem2 = 0.f, mem3 = 0.f;
    float spk0 = 0.f, spk1 = 0.f, spk2 = 0.f, spk3 = 0.f;

    const float BETA = 10.0f;
    const float TAU = 0.25f;

#pragma unroll
    for (int t = 0; t < T_STEPS; ++t) {
        float4 xt = xv[(size_t)t * (size_t)n4 + (size_t)i];

        float u0 = TAU * mem0 * (1.0f - spk0) + xt.x;
        float u1 = TAU * mem1 * (1.0f - spk1) + xt.y;
        float u2 = TAU * mem2 * (1.0f - spk2) + xt.z;
        float u3 = TAU * mem3 * (1.0f - spk3) + xt.w;

        float s0 = 0.f, s1 = 0.f, s2 = 0.f, s3 = 0.f;
#pragma unroll
        for (int k = 0; k < NTHR; ++k) {
            s0 += fast_sigmoid(BETA * (u0 - thr[k]));
            s1 += fast_sigmoid(BETA * (u1 - thr[k]));
            s2 += fast_sigmoid(BETA * (u2 - thr[k]));
            s3 += fast_sigmoid(BETA * (u3 - thr[k]));
        }

        mem0 = u0; mem1 = u1; mem2 = u2; mem3 = u3;
        spk0 = s0; spk1 = s1; spk2 = s2; spk3 = s3;

        float4 o; o.x = s0; o.y = s1; o.z = s2; o.w = s3;
        ov[(size_t)t * (size_t)n4 + (size_t)i] = o;
    }
}

extern "C" void kernel_launch(void* const* d_in, const int* in_sizes, int n_in,
                              void* d_out, int out_size, void* d_ws, size_t ws_size,
                              hipStream_t stream) {
    const float* x = (const float*)d_in[0];
    const float* raw_thr = (const float*)d_in[1];
    float* out = (float*)d_out;

    // in_sizes[0] = T*B*C*H*W = 67108864; per-timestep spatial count:
    int n_spatial = in_sizes[0] / T_STEPS;   // 4,194,304
    int n4 = n_spatial / 4;                  // 1,048,576 float4 groups

    const int block = 256;
    const int grid = (n4 + block - 1) / block;  // 4096 blocks

    lif_spike_kernel<<<grid, block, 0, stream>>>(x, raw_thr, out, n4);
}